// Round 1
// baseline (2241.347 us; speedup 1.0000x reference)
//
#include <hip/hip_runtime.h>

// Problem constants (from reference):
//   T=4 tables, E=1,000,000 rows/table, D=128 dim, B=8192 bags/table, L=32 bag length
//   indices: [T, B, L] int32 (JAX x64 disabled -> int64 request canonicalizes to int32)
//   weights: [T, E, D] float32
//   out:     [B, T*D]  float32  (pooled[t,b,:] written at out[b, t*128 .. t*128+127])

#define TBL_T 4
#define TBL_E 1000000LL
#define TBL_D 128
#define TBL_B 8192
#define TBL_L 32

// One 32-lane segment per bag; each lane owns one float4 (4 floats) of the D=128 row.
// 256-thread block => 8 bags/block. Row read = 32 lanes x 16 B = 512 B fully coalesced.
__global__ __launch_bounds__(256) void embedding_bag_sum_kernel(
    const int*   __restrict__ indices,   // [T*B*L]
    const float* __restrict__ weights,   // [T*E*D]
    float*       __restrict__ out)       // [B*T*D]
{
    const int lane       = threadIdx.x & 31;   // float4 slot within the row (32 x float4 = 128 f32)
    const int bagInBlock = threadIdx.x >> 5;   // 0..7
    const int g = blockIdx.x * 8 + bagInBlock; // bag id in [0, T*B)
    const int t = g >> 13;                     // g / B  (B = 8192)
    const int b = g & (TBL_B - 1);             // g % B

    // Preload this bag's 32 indices, one per lane (coalesced 128 B per segment).
    const int* bagIdx = indices + (size_t)g * TBL_L;
    const int myIdx = bagIdx[lane];

    const float4* tbl = (const float4*)(weights + (size_t)t * TBL_E * TBL_D);

    float4 acc = make_float4(0.f, 0.f, 0.f, 0.f);
#pragma unroll
    for (int l = 0; l < TBL_L; ++l) {
        const int idx = __shfl(myIdx, l, 32);          // broadcast within 32-lane segment
        const float4 v = tbl[(size_t)idx * (TBL_D / 4) + lane];
        acc.x += v.x; acc.y += v.y; acc.z += v.z; acc.w += v.w;
    }

    // out[b, t*D + lane*4 .. +3]
    float4* outv = (float4*)(out + (size_t)b * (TBL_T * TBL_D) + t * TBL_D);
    outv[lane] = acc;
}

extern "C" void kernel_launch(void* const* d_in, const int* in_sizes, int n_in,
                              void* d_out, int out_size, void* d_ws, size_t ws_size,
                              hipStream_t stream) {
    const int*   indices = (const int*)d_in[0];
    const float* weights = (const float*)d_in[1];
    float*       out     = (float*)d_out;

    const int numBags = TBL_T * TBL_B;          // 32768
    const int block   = 256;                    // 8 bags per block
    const int grid    = numBags / 8;            // 4096 blocks

    embedding_bag_sum_kernel<<<grid, block, 0, stream>>>(indices, weights, out);
}